// Round 1
// baseline (859.310 us; speedup 1.0000x reference)
//
#include <hip/hip_runtime.h>
#include <math.h>

// Problem constants (fixed by reference)
constexpr int I_N = 40000, U_N = 30000, F_N = 30000;
constexpr int NN   = 100000;           // total nodes
constexpr int EE   = 1200000;          // edges (without self loops)
constexpr int ETOT = EE + NN;          // edges + self loops

__device__ __forceinline__ float leaky(float x){ return x > 0.f ? x : 0.2f*x; }

// ---------------- init: fin = x0 = concat(emb_item, emb_user, emb_fet) ----------------
__global__ __launch_bounds__(256) void init_fin_k(
    const float* __restrict__ ei, const float* __restrict__ eu, const float* __restrict__ ef,
    float* __restrict__ fin)
{
  int i = blockIdx.x*256 + threadIdx.x;        // over NN*16 float4 (64 floats per node)
  if (i >= NN*16) return;
  float4 v;
  if      (i <  I_N*16)       v = ((const float4*)ei)[i];
  else if (i < (I_N+U_N)*16)  v = ((const float4*)eu)[i - I_N*16];
  else                        v = ((const float4*)ef)[i - (I_N+U_N)*16];
  ((float4*)fin)[i] = v;
}

// ---------------- CSR build ----------------
__global__ __launch_bounds__(256) void init_counts_k(int* counts){
  int i = blockIdx.x*256 + threadIdx.x;
  if (i < NN) counts[i] = 1;                   // self loop
}

__global__ __launch_bounds__(256) void count_k(const int* __restrict__ edst, int* counts){
  int e = blockIdx.x*256 + threadIdx.x;
  if (e < EE) atomicAdd(&counts[edst[e]], 1);
}

__global__ __launch_bounds__(256) void scan_blk_k(const int* __restrict__ counts,
                                                  int* __restrict__ row_start,
                                                  int* __restrict__ partials){
  __shared__ int sm[256];
  int t = threadIdx.x, i = blockIdx.x*256 + t;
  int v = (i < NN) ? counts[i] : 0;
  sm[t] = v; __syncthreads();
  for (int off=1; off<256; off<<=1){
    int x = (t >= off) ? sm[t-off] : 0;
    __syncthreads();
    sm[t] += x;
    __syncthreads();
  }
  if (i < NN) row_start[i] = sm[t] - v;        // exclusive
  if (t == 255) partials[blockIdx.x] = sm[255];
}

__global__ __launch_bounds__(512) void scan_part_k(int* partials, int nb){
  __shared__ int sm[512];
  int t = threadIdx.x;
  int v = (t < nb) ? partials[t] : 0;
  sm[t] = v; __syncthreads();
  for (int off=1; off<512; off<<=1){
    int x = (t >= off) ? sm[t-off] : 0;
    __syncthreads();
    sm[t] += x;
    __syncthreads();
  }
  if (t < nb) partials[t] = sm[t] - v;         // exclusive
}

__global__ __launch_bounds__(256) void scan_fix_k(int* row_start, const int* __restrict__ partials,
                                                  int* cursor){
  int i = blockIdx.x*256 + threadIdx.x;
  if (i < NN){
    int v = row_start[i] + partials[blockIdx.x];
    row_start[i] = v;
    cursor[i]    = v;
  }
  if (i == 0) row_start[NN] = ETOT;
}

__global__ __launch_bounds__(256) void scatter_k(const int* __restrict__ esrc,
                                                 const int* __restrict__ edst,
                                                 int* cursor, int* __restrict__ colsrc){
  int e = blockIdx.x*256 + threadIdx.x;
  if (e < EE){
    int d = edst[e];
    int p = atomicAdd(&cursor[d], 1);
    colsrc[p] = esrc[e];
  } else if (e < ETOT){
    int i = e - EE;                            // self loop
    int p = atomicAdd(&cursor[i], 1);
    colsrc[p] = i;
  }
}

// ---------------- GEMM (+ fused attention dot products) ----------------
// Computes XW[:, coff:coff+C] = X @ W[:, coff:coff+C]  (W row-major K x CTOT)
// and asrc[n,h], adst[n,h] for the heads covered by this column slice.
template<int K, int C, int CTOT>
__global__ __launch_bounds__(256) void gemm_att_k(
    const float* __restrict__ X, const float* __restrict__ W, int coff,
    const float* __restrict__ atts, const float* __restrict__ attd,
    float* __restrict__ XW, float* __restrict__ asrc, float* __restrict__ adst)
{
  constexpr int TPR  = C/4;        // threads per row slice
  constexpr int RPB  = 512/TPR;    // rows per block (each thread does 2 rows)
  constexpr int HALF = RPB/2;
  constexpr int HTOT = CTOT/64;
  __shared__ float Ws[K*C];
  __shared__ float Xs[RPB*K];
  int t = threadIdx.x;
  long rbase = (long)blockIdx.x * RPB;

  for (int i = t; i < K*C/4; i += 256){
    int k = i/(C/4), c = (i%(C/4))*4;
    *(float4*)&Ws[k*C + c] = *(const float4*)&W[(long)k*CTOT + coff + c];
  }
  for (int i = t; i < RPB*K/4; i += 256)
    ((float4*)Xs)[i] = ((const float4*)(X + rbase*K))[i];
  __syncthreads();

  int rA = t/TPR, rB = rA + HALF;
  int c4 = (t%TPR)*4;
  const float* xa = Xs + rA*K;
  const float* xb = Xs + rB*K;
  float4 a0 = make_float4(0,0,0,0), a1 = make_float4(0,0,0,0);
  #pragma unroll 8
  for (int k = 0; k < K; ++k){
    float4 w = *(const float4*)&Ws[k*C + c4];
    float va = xa[k], vb = xb[k];
    a0.x = fmaf(va,w.x,a0.x); a0.y = fmaf(va,w.y,a0.y);
    a0.z = fmaf(va,w.z,a0.z); a0.w = fmaf(va,w.w,a0.w);
    a1.x = fmaf(vb,w.x,a1.x); a1.y = fmaf(vb,w.y,a1.y);
    a1.z = fmaf(vb,w.z,a1.z); a1.w = fmaf(vb,w.w,a1.w);
  }

  int gc = coff + c4;
  int head = gc >> 6, d0 = gc & 63;
  const float* as = atts + head*64 + d0;
  const float* ad = attd + head*64 + d0;
  float ps0 = a0.x*as[0]+a0.y*as[1]+a0.z*as[2]+a0.w*as[3];
  float pd0 = a0.x*ad[0]+a0.y*ad[1]+a0.z*ad[2]+a0.w*ad[3];
  float ps1 = a1.x*as[0]+a1.y*as[1]+a1.z*as[2]+a1.w*as[3];
  float pd1 = a1.x*ad[0]+a1.y*ad[1]+a1.z*ad[2]+a1.w*ad[3];
  #pragma unroll
  for (int m = 1; m < 16; m <<= 1){
    ps0 += __shfl_xor(ps0, m, 64);
    pd0 += __shfl_xor(pd0, m, 64);
    ps1 += __shfl_xor(ps1, m, 64);
    pd1 += __shfl_xor(pd1, m, 64);
  }
  long ra = rbase + rA, rb = rbase + rB;
  if ((t & 15) == 0){
    asrc[ra*HTOT + head] = ps0; adst[ra*HTOT + head] = pd0;
    asrc[rb*HTOT + head] = ps1; adst[rb*HTOT + head] = pd1;
  }
  *(float4*)&XW[ra*CTOT + gc] = a0;
  *(float4*)&XW[rb*CTOT + gc] = a1;
}

// ---------------- per-dst aggregation (softmax + weighted sum), 1 wave per node ----------------
template<int H>
__global__ __launch_bounds__(256) void aggregate_k(
    const float* __restrict__ XW, const float* __restrict__ asrc, const float* __restrict__ adst,
    const int* __restrict__ row_start, const int* __restrict__ colsrc,
    const float* __restrict__ bias, float* __restrict__ hbuf, float* __restrict__ fin,
    float* __restrict__ mbuf, float* __restrict__ invden, float finScale)
{
  constexpr int C = H*64;
  int wid  = (blockIdx.x*256 + threadIdx.x) >> 6;
  int lane = threadIdx.x & 63;
  if (wid >= NN) return;
  int n0 = row_start[wid], n1 = row_start[wid+1];

  float ad[H], mx[H];
  #pragma unroll
  for (int h = 0; h < H; ++h){ ad[h] = adst[wid*H + h]; mx[h] = -3.402823466e38f; }

  // pass 1: wave-parallel max over incoming edges
  for (int base = n0; base < n1; base += 64){
    int cnt = n1 - base; if (cnt > 64) cnt = 64;
    if (lane < cnt){
      int s = colsrc[base + lane];
      #pragma unroll
      for (int h = 0; h < H; ++h){
        float e = leaky(asrc[s*H + h] + ad[h]);
        mx[h] = fmaxf(mx[h], e);
      }
    }
  }
  #pragma unroll
  for (int h = 0; h < H; ++h)
    for (int m = 1; m < 64; m <<= 1) mx[h] = fmaxf(mx[h], __shfl_xor(mx[h], m, 64));

  // pass 2: p, denom, weighted accumulation of XW[src]
  float den[H], acc[H];
  #pragma unroll
  for (int h = 0; h < H; ++h){ den[h] = 0.f; acc[h] = 0.f; }
  for (int base = n0; base < n1; base += 64){
    int cnt = n1 - base; if (cnt > 64) cnt = 64;
    int s = 0; float p[H];
    #pragma unroll
    for (int h = 0; h < H; ++h) p[h] = 0.f;
    if (lane < cnt){
      s = colsrc[base + lane];
      #pragma unroll
      for (int h = 0; h < H; ++h){
        float e = leaky(asrc[s*H + h] + ad[h]);
        p[h] = __expf(e - mx[h]);
        den[h] += p[h];
      }
    }
    for (int j = 0; j < cnt; ++j){
      int sj = __shfl(s, j, 64);
      const float* xp = XW + (long)sj*C;
      #pragma unroll
      for (int h = 0; h < H; ++h){
        float q = __shfl(p[h], j, 64);
        acc[h] = fmaf(q, xp[h*64 + lane], acc[h]);
      }
    }
  }
  #pragma unroll
  for (int h = 0; h < H; ++h)
    for (int m = 1; m < 64; m <<= 1) den[h] += __shfl_xor(den[h], m, 64);

  float fadd = 0.f;
  #pragma unroll
  for (int h = 0; h < H; ++h){
    float id  = 1.0f/(den[h] + 1e-16f);
    float out = acc[h]*id + bias[h*64 + lane];
    if (hbuf) hbuf[(long)wid*C + h*64 + lane] = fmaxf(out, 0.f);
    fadd += out;
    if (lane == 0){ mbuf[wid*H + h] = mx[h]; invden[wid*H + h] = id; }
  }
  fin[(long)wid*64 + lane] += fadd * finScale;   // += e_k (head mean) or x3
}

// ---------------- alpha output (edge-parallel, coalesced writes) ----------------
template<int H>
__global__ __launch_bounds__(256) void alpha_kk(
    const int* __restrict__ esrc, const int* __restrict__ edst,
    const float* __restrict__ asrc, const float* __restrict__ adst,
    const float* __restrict__ mbuf, const float* __restrict__ invden,
    float* __restrict__ out)
{
  int e = blockIdx.x*256 + threadIdx.x;
  if (e >= ETOT) return;
  int s, d;
  if (e < EE){ s = esrc[e]; d = edst[e]; } else { s = d = e - EE; }
  #pragma unroll
  for (int h = 0; h < H; ++h){
    float ev = leaky(asrc[s*H + h] + adst[d*H + h]);
    float p  = __expf(ev - mbuf[d*H + h]);
    out[(long)e*H + h] = p * invden[d*H + h];
  }
}

// ---------------- final: (x0+e1+e2+x3)/4 written twice (slices + final) ----------------
__global__ __launch_bounds__(256) void final_kk(const float* __restrict__ fin, float* __restrict__ out){
  int i = blockIdx.x*256 + threadIdx.x;          // over NN*16 float4
  if (i >= NN*16) return;
  float4 v = ((const float4*)fin)[i];
  v.x *= 0.25f; v.y *= 0.25f; v.z *= 0.25f; v.w *= 0.25f;
  ((float4*)out)[i]         = v;                 // item|user|fet slices
  ((float4*)out)[i + NN*16] = v;                 // final
}

extern "C" void kernel_launch(void* const* d_in, const int* in_sizes, int n_in,
                              void* d_out, int out_size, void* d_ws, size_t ws_size,
                              hipStream_t stream)
{
  (void)in_sizes; (void)n_in; (void)out_size; (void)ws_size;
  const int*   eidx  = (const int*)d_in[0];
  const int*   esrc  = eidx;
  const int*   edst  = eidx + EE;
  const float* emb_i = (const float*)d_in[1];
  const float* emb_u = (const float*)d_in[2];
  const float* emb_f = (const float*)d_in[3];
  const float* W1    = (const float*)d_in[4];
  const float* as1   = (const float*)d_in[5];
  const float* ad1   = (const float*)d_in[6];
  const float* b1    = (const float*)d_in[7];
  const float* W2    = (const float*)d_in[8];
  const float* as2   = (const float*)d_in[9];
  const float* ad2   = (const float*)d_in[10];
  const float* b2    = (const float*)d_in[11];
  const float* W3    = (const float*)d_in[12];
  const float* as3   = (const float*)d_in[13];
  const float* ad3   = (const float*)d_in[14];
  const float* b3    = (const float*)d_in[15];
  float* out = (float*)d_out;

  // workspace layout (256B aligned): ~142 MB total
  char* p = (char*)d_ws;
  auto alloc = [&](size_t bytes)->char* {
    char* r = p; p += (bytes + 255) & ~(size_t)255; return r;
  };
  float* fin    = (float*)alloc((size_t)NN*64*4);
  float* hbuf   = (float*)alloc((size_t)NN*128*4);
  float* xw     = (float*)alloc((size_t)NN*128*4);
  float* asrc   = (float*)alloc((size_t)NN*2*4);
  float* adst   = (float*)alloc((size_t)NN*2*4);
  float* mbuf   = (float*)alloc((size_t)NN*2*4);
  float* invd   = (float*)alloc((size_t)NN*2*4);
  int* counts    = (int*)alloc((size_t)NN*4);
  int* row_start = (int*)alloc((size_t)(NN+1)*4);
  int* cursor    = (int*)alloc((size_t)NN*4);
  int* colsrc    = (int*)alloc((size_t)ETOT*4);
  int* partials  = (int*)alloc(512*4);

  constexpr int NB_N  = (NN  +255)/256;   // 391
  constexpr int NB_E  = (EE  +255)/256;   // 4688
  constexpr int NB_ET = (ETOT+255)/256;   // 5079

  // x0 / fin init + CSR build (shared by all layers)
  init_fin_k   <<<(NN*16+255)/256,256,0,stream>>>(emb_i, emb_u, emb_f, fin);
  init_counts_k<<<NB_N ,256,0,stream>>>(counts);
  count_k      <<<NB_E ,256,0,stream>>>(edst, counts);
  scan_blk_k   <<<NB_N ,256,0,stream>>>(counts, row_start, partials);
  scan_part_k  <<<1    ,512,0,stream>>>(partials, NB_N);
  scan_fix_k   <<<NB_N ,256,0,stream>>>(row_start, partials, cursor);
  scatter_k    <<<NB_ET,256,0,stream>>>(esrc, edst, cursor, colsrc);

  // ---- Layer 1: K=64 -> C=128 (H=2) ----
  gemm_att_k<64,128,128><<<NN/16,256,0,stream>>>(fin, W1, 0, as1, ad1, xw, asrc, adst);
  aggregate_k<2><<<NN/4,256,0,stream>>>(xw, asrc, adst, row_start, colsrc, b1, hbuf, fin, mbuf, invd, 0.5f);
  alpha_kk<2><<<NB_ET,256,0,stream>>>(esrc, edst, asrc, adst, mbuf, invd, out + (size_t)12800000);

  // ---- Layer 2: K=128 -> C=128 (H=2), split into two 64-col slices to keep LDS <= 48KB ----
  gemm_att_k<128,64,128><<<NN/32,256,0,stream>>>(hbuf, W2,  0, as2, ad2, xw, asrc, adst);
  gemm_att_k<128,64,128><<<NN/32,256,0,stream>>>(hbuf, W2, 64, as2, ad2, xw, asrc, adst);
  aggregate_k<2><<<NN/4,256,0,stream>>>(xw, asrc, adst, row_start, colsrc, b2, hbuf, fin, mbuf, invd, 0.5f);
  alpha_kk<2><<<NB_ET,256,0,stream>>>(esrc, edst, asrc, adst, mbuf, invd, out + (size_t)15400000);

  // ---- Layer 3: K=128 -> C=64 (H=1, mean over 1 head = identity) ----
  gemm_att_k<128,64,64><<<NN/32,256,0,stream>>>(hbuf, W3, 0, as3, ad3, xw, asrc, adst);
  aggregate_k<1><<<NN/4,256,0,stream>>>(xw, asrc, adst, row_start, colsrc, b3, nullptr, fin, mbuf, invd, 1.0f);
  alpha_kk<1><<<NB_ET,256,0,stream>>>(esrc, edst, asrc, adst, mbuf, invd, out + (size_t)18000000);

  // ---- final = (x0 + e1 + e2 + x3)/4, written to both output slots ----
  final_kk<<<(NN*16+255)/256,256,0,stream>>>(fin, out);
}

// Round 2
// 747.785 us; speedup vs baseline: 1.1491x; 1.1491x over previous
//
#include <hip/hip_runtime.h>
#include <math.h>

// Problem constants (fixed by reference)
constexpr int I_N = 40000, U_N = 30000, F_N = 30000;
constexpr int NN   = 100000;           // total nodes
constexpr int EE   = 1200000;          // edges (without self loops)
constexpr int ETOT = EE + NN;          // edges + self loops

__device__ __forceinline__ float leaky(float x){ return x > 0.f ? x : 0.2f*x; }

// ---------------- init: fin = x0 = concat(emb_item, emb_user, emb_fet) ----------------
__global__ __launch_bounds__(256) void init_fin_k(
    const float* __restrict__ ei, const float* __restrict__ eu, const float* __restrict__ ef,
    float* __restrict__ fin)
{
  int i = blockIdx.x*256 + threadIdx.x;        // over NN*16 float4 (64 floats per node)
  if (i >= NN*16) return;
  float4 v;
  if      (i <  I_N*16)       v = ((const float4*)ei)[i];
  else if (i < (I_N+U_N)*16)  v = ((const float4*)eu)[i - I_N*16];
  else                        v = ((const float4*)ef)[i - (I_N+U_N)*16];
  ((float4*)fin)[i] = v;
}

// ---------------- CSR build ----------------
__global__ __launch_bounds__(256) void init_counts_k(int* counts){
  int i = blockIdx.x*256 + threadIdx.x;
  if (i < NN) counts[i] = 1;                   // self loop
}

__global__ __launch_bounds__(256) void count_k(const int* __restrict__ edst, int* counts){
  int e = blockIdx.x*256 + threadIdx.x;
  if (e < EE) atomicAdd(&counts[edst[e]], 1);
}

__global__ __launch_bounds__(256) void scan_blk_k(const int* __restrict__ counts,
                                                  int* __restrict__ row_start,
                                                  int* __restrict__ partials){
  __shared__ int sm[256];
  int t = threadIdx.x, i = blockIdx.x*256 + t;
  int v = (i < NN) ? counts[i] : 0;
  sm[t] = v; __syncthreads();
  for (int off=1; off<256; off<<=1){
    int x = (t >= off) ? sm[t-off] : 0;
    __syncthreads();
    sm[t] += x;
    __syncthreads();
  }
  if (i < NN) row_start[i] = sm[t] - v;        // exclusive
  if (t == 255) partials[blockIdx.x] = sm[255];
}

__global__ __launch_bounds__(512) void scan_part_k(int* partials, int nb){
  __shared__ int sm[512];
  int t = threadIdx.x;
  int v = (t < nb) ? partials[t] : 0;
  sm[t] = v; __syncthreads();
  for (int off=1; off<512; off<<=1){
    int x = (t >= off) ? sm[t-off] : 0;
    __syncthreads();
    sm[t] += x;
    __syncthreads();
  }
  if (t < nb) partials[t] = sm[t] - v;         // exclusive
}

__global__ __launch_bounds__(256) void scan_fix_k(int* row_start, const int* __restrict__ partials,
                                                  int* cursor){
  int i = blockIdx.x*256 + threadIdx.x;
  if (i < NN){
    int v = row_start[i] + partials[blockIdx.x];
    row_start[i] = v;
    cursor[i]    = v;
  }
  if (i == 0) row_start[NN] = ETOT;
}

__global__ __launch_bounds__(256) void scatter_k(const int* __restrict__ esrc,
                                                 const int* __restrict__ edst,
                                                 int* cursor, int* __restrict__ colsrc){
  int e = blockIdx.x*256 + threadIdx.x;
  if (e < EE){
    int d = edst[e];
    int p = atomicAdd(&cursor[d], 1);
    colsrc[p] = esrc[e];
  } else if (e < ETOT){
    int i = e - EE;                            // self loop
    int p = atomicAdd(&cursor[i], 1);
    colsrc[p] = i;
  }
}

// ---------------- GEMM (+ fused attention dot products) ----------------
// XW = X @ W  (W row-major K x C), plus asrc[n,h]/adst[n,h] epilogue.
// K-tiled so big-K weights fit LDS and X is read exactly once.
template<int K, int C, int KTILE, int RPB>
__global__ __launch_bounds__(256) void gemm_att_k(
    const float* __restrict__ X, const float* __restrict__ W,
    const float* __restrict__ atts, const float* __restrict__ attd,
    float* __restrict__ XW, float* __restrict__ asrc, float* __restrict__ adst)
{
  constexpr int TPR   = C/4;        // threads per row
  constexpr int SLOTS = 256/TPR;    // concurrent rows
  constexpr int RPT   = RPB/SLOTS;  // rows per thread
  constexpr int HTOT  = C/64;
  __shared__ float Ws[KTILE*C];
  __shared__ float Xs[RPB*K];
  int t = threadIdx.x;
  long rbase = (long)blockIdx.x * RPB;

  for (int i = t; i < RPB*K/4; i += 256)
    ((float4*)Xs)[i] = ((const float4*)(X + rbase*K))[i];

  int slot = t / TPR;
  int c4   = (t % TPR)*4;
  float4 acc[RPT];
  #pragma unroll
  for (int i = 0; i < RPT; ++i) acc[i] = make_float4(0,0,0,0);

  for (int kt = 0; kt < K; kt += KTILE){
    __syncthreads();                            // Xs visible / Ws safe to overwrite
    for (int i = t; i < KTILE*C/4; i += 256)
      ((float4*)Ws)[i] = ((const float4*)(W + (long)kt*C))[i];
    __syncthreads();
    #pragma unroll 2
    for (int k = 0; k < KTILE; k += 4){
      float4 xv[RPT];
      #pragma unroll
      for (int i = 0; i < RPT; ++i)
        xv[i] = *(const float4*)&Xs[(slot + i*SLOTS)*K + kt + k];
      #pragma unroll
      for (int kk = 0; kk < 4; ++kk){
        float4 w = *(const float4*)&Ws[(k+kk)*C + c4];
        #pragma unroll
        for (int i = 0; i < RPT; ++i){
          float xvv = (kk==0)?xv[i].x:(kk==1)?xv[i].y:(kk==2)?xv[i].z:xv[i].w;
          acc[i].x = fmaf(xvv,w.x,acc[i].x); acc[i].y = fmaf(xvv,w.y,acc[i].y);
          acc[i].z = fmaf(xvv,w.z,acc[i].z); acc[i].w = fmaf(xvv,w.w,acc[i].w);
        }
      }
    }
  }

  int head = c4 >> 6;
  float4 as4 = *(const float4*)&atts[head*64 + (c4&63)];
  float4 ad4 = *(const float4*)&attd[head*64 + (c4&63)];
  #pragma unroll
  for (int i = 0; i < RPT; ++i){
    float ps = acc[i].x*as4.x + acc[i].y*as4.y + acc[i].z*as4.z + acc[i].w*as4.w;
    float pd = acc[i].x*ad4.x + acc[i].y*ad4.y + acc[i].z*ad4.z + acc[i].w*ad4.w;
    #pragma unroll
    for (int m = 1; m < 16; m <<= 1){
      ps += __shfl_xor(ps, m, 64);
      pd += __shfl_xor(pd, m, 64);
    }
    long r = rbase + slot + i*SLOTS;
    if ((t & 15) == 0){
      asrc[r*HTOT + head] = ps; adst[r*HTOT + head] = pd;
    }
    *(float4*)&XW[r*C + c4] = acc[i];
  }
}

// ---------------- per-dst aggregation: online softmax + weighted sum, 1 wave/node --------
// H==2: lane owns float2 (d = lane*2, lane*2+1 of C=128); head = lane>>5.
// H==1: lane owns d = lane.
template<int H>
__global__ __launch_bounds__(256) void aggregate_k(
    const float* __restrict__ XW, const float* __restrict__ asrc, const float* __restrict__ adst,
    const int* __restrict__ row_start, const int* __restrict__ colsrc,
    const float* __restrict__ bias, float* __restrict__ hbuf, float* __restrict__ fin,
    float* __restrict__ pm, float finScale)
{
  int wid  = (blockIdx.x*256 + threadIdx.x) >> 6;
  int lane = threadIdx.x & 63;
  if (wid >= NN) return;
  int n0 = row_start[wid], n1 = row_start[wid+1];

  float ad[H];
  if constexpr (H==2){ float2 t = ((const float2*)adst)[wid]; ad[0]=t.x; ad[1]=t.y; }
  else                 ad[0] = adst[wid];

  float mx[H], den[H];
  #pragma unroll
  for (int h=0; h<H; ++h){ mx[h] = -3.402823466e38f; den[h] = 0.f; }
  float accx = 0.f, accy = 0.f;

  for (int base = n0; base < n1; base += 64){
    int cnt = n1 - base; if (cnt > 64) cnt = 64;
    int s = 0;
    float e[H], p[H];
    #pragma unroll
    for (int h=0; h<H; ++h) e[h] = -3.402823466e38f;
    if (lane < cnt){
      s = colsrc[base + lane];
      if constexpr (H==2){
        float2 a = ((const float2*)asrc)[s];
        e[0] = leaky(a.x + ad[0]); e[1] = leaky(a.y + ad[1]);
      } else {
        e[0] = leaky(asrc[s] + ad[0]);
      }
    }
    float sc[H];
    #pragma unroll
    for (int h=0; h<H; ++h){
      float bm = e[h];
      #pragma unroll
      for (int m=1; m<64; m<<=1) bm = fmaxf(bm, __shfl_xor(bm, m, 64));
      float nm = fmaxf(mx[h], bm);
      sc[h] = __expf(mx[h] - nm);
      p[h]  = (lane < cnt) ? __expf(e[h] - nm) : 0.f;
      den[h] = den[h]*sc[h] + p[h];
      mx[h] = nm;
    }
    if constexpr (H==2){
      float myS = (lane < 32) ? sc[0] : sc[1];
      accx *= myS; accy *= myS;
    } else {
      accx *= sc[0];
    }

    int j = 0;
    if constexpr (H==2){
      for (; j+4 <= cnt; j += 4){
        float2 v[4]; float q[4];
        #pragma unroll
        for (int u=0; u<4; ++u){
          int su = __shfl(s, j+u, 64);
          v[u] = ((const float2*)XW)[(long)su*64 + lane];
          float q0 = __shfl(p[0], j+u, 64);
          float q1 = __shfl(p[1], j+u, 64);
          q[u] = (lane < 32) ? q0 : q1;
        }
        #pragma unroll
        for (int u=0; u<4; ++u){
          accx = fmaf(q[u], v[u].x, accx);
          accy = fmaf(q[u], v[u].y, accy);
        }
      }
      for (; j < cnt; ++j){
        int su = __shfl(s, j, 64);
        float2 v = ((const float2*)XW)[(long)su*64 + lane];
        float q0 = __shfl(p[0], j, 64);
        float q1 = __shfl(p[1], j, 64);
        float q = (lane < 32) ? q0 : q1;
        accx = fmaf(q, v.x, accx);
        accy = fmaf(q, v.y, accy);
      }
    } else {
      for (; j+8 <= cnt; j += 8){
        float v[8], q[8];
        #pragma unroll
        for (int u=0; u<8; ++u){
          int su = __shfl(s, j+u, 64);
          v[u] = XW[(long)su*64 + lane];
          q[u] = __shfl(p[0], j+u, 64);
        }
        #pragma unroll
        for (int u=0; u<8; ++u) accx = fmaf(q[u], v[u], accx);
      }
      for (; j < cnt; ++j){
        int su = __shfl(s, j, 64);
        float v = XW[(long)su*64 + lane];
        float q = __shfl(p[0], j, 64);
        accx = fmaf(q, v, accx);
      }
    }
  }

  float idv[H];
  #pragma unroll
  for (int h=0; h<H; ++h){
    #pragma unroll
    for (int m=1; m<64; m<<=1) den[h] += __shfl_xor(den[h], m, 64);
    idv[h] = 1.0f/(den[h] + 1e-16f);
  }

  if constexpr (H==2){
    float myId = (lane < 32) ? idv[0] : idv[1];
    float2 b = ((const float2*)bias)[lane];
    float ox = accx*myId + b.x;
    float oy = accy*myId + b.y;
    if (hbuf) ((float2*)hbuf)[(long)wid*64 + lane] = make_float2(fmaxf(ox,0.f), fmaxf(oy,0.f));
    float fx = ox + __shfl_xor(ox, 32, 64);     // head0 + head1 per d
    float fy = oy + __shfl_xor(oy, 32, 64);
    if (lane < 32){
      float2* fp = (float2*)&fin[(long)wid*64 + lane*2];
      float2 cur = *fp;
      cur.x += fx*finScale; cur.y += fy*finScale;
      *fp = cur;
    }
    if (lane == 0) ((float4*)pm)[wid] = make_float4(mx[0], idv[0], mx[1], idv[1]);
  } else {
    float o = accx*idv[0] + bias[lane];
    fin[(long)wid*64 + lane] += o*finScale;
    if (lane == 0) ((float2*)pm)[wid] = make_float2(mx[0], idv[0]);
  }
}

// ---------------- alpha output (edge-parallel, coalesced writes) ----------------
template<int H>
__global__ __launch_bounds__(256) void alpha_kk(
    const int* __restrict__ esrc, const int* __restrict__ edst,
    const float* __restrict__ asrc, const float* __restrict__ adst,
    const float* __restrict__ pm, float* __restrict__ out)
{
  int e = blockIdx.x*256 + threadIdx.x;
  if (e >= ETOT) return;
  int s, d;
  if (e < EE){ s = esrc[e]; d = edst[e]; } else { s = d = e - EE; }
  if constexpr (H==2){
    float2 a  = ((const float2*)asrc)[s];
    float2 b  = ((const float2*)adst)[d];
    float4 mi = ((const float4*)pm)[d];
    float2 o;
    o.x = __expf(leaky(a.x + b.x) - mi.x) * mi.y;
    o.y = __expf(leaky(a.y + b.y) - mi.z) * mi.w;
    ((float2*)out)[e] = o;
  } else {
    float2 mi = ((const float2*)pm)[d];
    out[e] = __expf(leaky(asrc[s] + adst[d]) - mi.x) * mi.y;
  }
}

// ---------------- final: (x0+e1+e2+x3)/4 written twice (slices + final) ----------------
__global__ __launch_bounds__(256) void final_kk(const float* __restrict__ fin, float* __restrict__ out){
  int i = blockIdx.x*256 + threadIdx.x;          // over NN*16 float4
  if (i >= NN*16) return;
  float4 v = ((const float4*)fin)[i];
  v.x *= 0.25f; v.y *= 0.25f; v.z *= 0.25f; v.w *= 0.25f;
  ((float4*)out)[i]         = v;                 // item|user|fet slices
  ((float4*)out)[i + NN*16] = v;                 // final
}

extern "C" void kernel_launch(void* const* d_in, const int* in_sizes, int n_in,
                              void* d_out, int out_size, void* d_ws, size_t ws_size,
                              hipStream_t stream)
{
  (void)in_sizes; (void)n_in; (void)out_size; (void)ws_size;
  const int*   eidx  = (const int*)d_in[0];
  const int*   esrc  = eidx;
  const int*   edst  = eidx + EE;
  const float* emb_i = (const float*)d_in[1];
  const float* emb_u = (const float*)d_in[2];
  const float* emb_f = (const float*)d_in[3];
  const float* W1    = (const float*)d_in[4];
  const float* as1   = (const float*)d_in[5];
  const float* ad1   = (const float*)d_in[6];
  const float* b1    = (const float*)d_in[7];
  const float* W2    = (const float*)d_in[8];
  const float* as2   = (const float*)d_in[9];
  const float* ad2   = (const float*)d_in[10];
  const float* b2    = (const float*)d_in[11];
  const float* W3    = (const float*)d_in[12];
  const float* as3   = (const float*)d_in[13];
  const float* ad3   = (const float*)d_in[14];
  const float* b3    = (const float*)d_in[15];
  float* out = (float*)d_out;

  // workspace layout (256B aligned)
  char* p = (char*)d_ws;
  auto alloc = [&](size_t bytes)->char* {
    char* r = p; p += (bytes + 255) & ~(size_t)255; return r;
  };
  float* fin    = (float*)alloc((size_t)NN*64*4);
  float* hbuf   = (float*)alloc((size_t)NN*128*4);
  float* xw     = (float*)alloc((size_t)NN*128*4);
  float* asrc   = (float*)alloc((size_t)NN*2*4);
  float* adst   = (float*)alloc((size_t)NN*2*4);
  float* pm     = (float*)alloc((size_t)NN*4*4);   // (m0,id0,m1,id1) or (m,id)
  int* counts    = (int*)alloc((size_t)NN*4);
  int* row_start = (int*)alloc((size_t)(NN+1)*4);
  int* cursor    = (int*)alloc((size_t)NN*4);
  int* colsrc    = (int*)alloc((size_t)ETOT*4);
  int* partials  = (int*)alloc(512*4);

  constexpr int NB_N  = (NN  +255)/256;   // 391
  constexpr int NB_E  = (EE  +255)/256;   // 4688
  constexpr int NB_ET = (ETOT+255)/256;   // 5079

  // x0 / fin init + CSR build (shared by all layers)
  init_fin_k   <<<(NN*16+255)/256,256,0,stream>>>(emb_i, emb_u, emb_f, fin);
  init_counts_k<<<NB_N ,256,0,stream>>>(counts);
  count_k      <<<NB_E ,256,0,stream>>>(edst, counts);
  scan_blk_k   <<<NB_N ,256,0,stream>>>(counts, row_start, partials);
  scan_part_k  <<<1    ,512,0,stream>>>(partials, NB_N);
  scan_fix_k   <<<NB_N ,256,0,stream>>>(row_start, partials, cursor);
  scatter_k    <<<NB_ET,256,0,stream>>>(esrc, edst, cursor, colsrc);

  // ---- Layer 1: K=64 -> C=128 (H=2) ----
  gemm_att_k<64,128,64,32><<<NN/32,256,0,stream>>>(fin, W1, as1, ad1, xw, asrc, adst);
  aggregate_k<2><<<NN/4,256,0,stream>>>(xw, asrc, adst, row_start, colsrc, b1, hbuf, fin, pm, 0.5f);
  alpha_kk<2><<<NB_ET,256,0,stream>>>(esrc, edst, asrc, adst, pm, out + (size_t)12800000);

  // ---- Layer 2: K=128 -> C=128 (H=2), K-tiled, hbuf read once ----
  gemm_att_k<128,128,64,32><<<NN/32,256,0,stream>>>(hbuf, W2, as2, ad2, xw, asrc, adst);
  aggregate_k<2><<<NN/4,256,0,stream>>>(xw, asrc, adst, row_start, colsrc, b2, hbuf, fin, pm, 0.5f);
  alpha_kk<2><<<NB_ET,256,0,stream>>>(esrc, edst, asrc, adst, pm, out + (size_t)15400000);

  // ---- Layer 3: K=128 -> C=64 (H=1) ----
  gemm_att_k<128,64,128,32><<<NN/32,256,0,stream>>>(hbuf, W3, as3, ad3, xw, asrc, adst);
  aggregate_k<1><<<NN/4,256,0,stream>>>(xw, asrc, adst, row_start, colsrc, b3, nullptr, fin, pm, 1.0f);
  alpha_kk<1><<<NB_ET,256,0,stream>>>(esrc, edst, asrc, adst, pm, out + (size_t)18000000);

  // ---- final = (x0 + e1 + e2 + x3)/4, written to both output slots ----
  final_kk<<<(NN*16+255)/256,256,0,stream>>>(fin, out);
}

// Round 3
// 694.125 us; speedup vs baseline: 1.2380x; 1.0773x over previous
//
#include <hip/hip_runtime.h>
#include <math.h>

// Problem constants (fixed by reference)
constexpr int I_N = 40000, U_N = 30000, F_N = 30000;
constexpr int NN   = 100000;           // total nodes
constexpr int EE   = 1200000;          // edges (without self loops)
constexpr int ETOT = EE + NN;          // edges + self loops

__device__ __forceinline__ float leaky(float x){ return x > 0.f ? x : 0.2f*x; }

// ---------------- CSR build ----------------
__global__ __launch_bounds__(256) void init_counts_k(int* counts){
  int i = blockIdx.x*256 + threadIdx.x;
  if (i < NN) counts[i] = 1;                   // self loop
}

__global__ __launch_bounds__(256) void count_k(const int* __restrict__ edst, int* counts){
  int e = blockIdx.x*256 + threadIdx.x;
  if (e < EE) atomicAdd(&counts[edst[e]], 1);
}

__global__ __launch_bounds__(256) void scan_blk_k(const int* __restrict__ counts,
                                                  int* __restrict__ row_start,
                                                  int* __restrict__ partials){
  __shared__ int sm[256];
  int t = threadIdx.x, i = blockIdx.x*256 + t;
  int v = (i < NN) ? counts[i] : 0;
  sm[t] = v; __syncthreads();
  for (int off=1; off<256; off<<=1){
    int x = (t >= off) ? sm[t-off] : 0;
    __syncthreads();
    sm[t] += x;
    __syncthreads();
  }
  if (i < NN) row_start[i] = sm[t] - v;        // exclusive
  if (t == 255) partials[blockIdx.x] = sm[255];
}

__global__ __launch_bounds__(512) void scan_part_k(int* partials, int nb){
  __shared__ int sm[512];
  int t = threadIdx.x;
  int v = (t < nb) ? partials[t] : 0;
  sm[t] = v; __syncthreads();
  for (int off=1; off<512; off<<=1){
    int x = (t >= off) ? sm[t-off] : 0;
    __syncthreads();
    sm[t] += x;
    __syncthreads();
  }
  if (t < nb) partials[t] = sm[t] - v;         // exclusive
}

__global__ __launch_bounds__(256) void scan_fix_k(int* row_start, const int* __restrict__ partials,
                                                  int* cursor){
  int i = blockIdx.x*256 + threadIdx.x;
  if (i < NN){
    int v = row_start[i] + partials[blockIdx.x];
    row_start[i] = v;
    cursor[i]    = v;
  }
  if (i == 0) row_start[NN] = ETOT;
}

__global__ __launch_bounds__(256) void scatter_k(const int* __restrict__ esrc,
                                                 const int* __restrict__ edst,
                                                 int* cursor, int* __restrict__ colsrc,
                                                 int* __restrict__ eids){
  int e = blockIdx.x*256 + threadIdx.x;
  if (e < EE){
    int d = edst[e];
    int p = atomicAdd(&cursor[d], 1);
    colsrc[p] = esrc[e];
    eids[p]   = e;
  } else if (e < ETOT){
    int i = e - EE;                            // self loop
    int p = atomicAdd(&cursor[i], 1);
    colsrc[p] = i;
    eids[p]   = e;
  }
}

// ---------------- GEMM (+ fused attention dot products) ----------------
// XW = X @ W (W row-major K x C), plus asrc/adst epilogue. K-tiled.
// CONCAT: X is the virtual concat [Xa;Xb;Xc] (embeddings), row-width K.
template<int K, int C, int KTILE, int RPB, bool CONCAT>
__global__ __launch_bounds__(256) void gemm_att_k(
    const float* __restrict__ Xa, const float* __restrict__ Xb, const float* __restrict__ Xc,
    const float* __restrict__ W,
    const float* __restrict__ atts, const float* __restrict__ attd,
    float* __restrict__ XW, float* __restrict__ asrc, float* __restrict__ adst)
{
  constexpr int TPR   = C/4;        // threads per row
  constexpr int SLOTS = 256/TPR;    // concurrent rows
  constexpr int RPT   = RPB/SLOTS;  // rows per thread
  constexpr int HTOT  = C/64;
  __shared__ float Ws[KTILE*C];
  __shared__ float Xs[RPB*K];
  int t = threadIdx.x;
  long rbase = (long)blockIdx.x * RPB;

  if constexpr (CONCAT){
    for (int i = t; i < RPB*K/4; i += 256){
      long gi = rbase*(K/4) + i;               // float4 index in concat space
      float4 v;
      if      (gi < (long)I_N*(K/4))          v = ((const float4*)Xa)[gi];
      else if (gi < (long)(I_N+U_N)*(K/4))    v = ((const float4*)Xb)[gi - (long)I_N*(K/4)];
      else                                    v = ((const float4*)Xc)[gi - (long)(I_N+U_N)*(K/4)];
      ((float4*)Xs)[i] = v;
    }
  } else {
    for (int i = t; i < RPB*K/4; i += 256)
      ((float4*)Xs)[i] = ((const float4*)(Xa + rbase*K))[i];
  }

  int slot = t / TPR;
  int c4   = (t % TPR)*4;
  float4 acc[RPT];
  #pragma unroll
  for (int i = 0; i < RPT; ++i) acc[i] = make_float4(0,0,0,0);

  for (int kt = 0; kt < K; kt += KTILE){
    __syncthreads();
    for (int i = t; i < KTILE*C/4; i += 256)
      ((float4*)Ws)[i] = ((const float4*)(W + (long)kt*C))[i];
    __syncthreads();
    #pragma unroll 2
    for (int k = 0; k < KTILE; k += 4){
      float4 xv[RPT];
      #pragma unroll
      for (int i = 0; i < RPT; ++i)
        xv[i] = *(const float4*)&Xs[(slot + i*SLOTS)*K + kt + k];
      #pragma unroll
      for (int kk = 0; kk < 4; ++kk){
        float4 w = *(const float4*)&Ws[(k+kk)*C + c4];
        #pragma unroll
        for (int i = 0; i < RPT; ++i){
          float xvv = (kk==0)?xv[i].x:(kk==1)?xv[i].y:(kk==2)?xv[i].z:xv[i].w;
          acc[i].x = fmaf(xvv,w.x,acc[i].x); acc[i].y = fmaf(xvv,w.y,acc[i].y);
          acc[i].z = fmaf(xvv,w.z,acc[i].z); acc[i].w = fmaf(xvv,w.w,acc[i].w);
        }
      }
    }
  }

  int head = c4 >> 6;
  float4 as4 = *(const float4*)&atts[head*64 + (c4&63)];
  float4 ad4 = *(const float4*)&attd[head*64 + (c4&63)];
  #pragma unroll
  for (int i = 0; i < RPT; ++i){
    float ps = acc[i].x*as4.x + acc[i].y*as4.y + acc[i].z*as4.z + acc[i].w*as4.w;
    float pd = acc[i].x*ad4.x + acc[i].y*ad4.y + acc[i].z*ad4.z + acc[i].w*ad4.w;
    #pragma unroll
    for (int m = 1; m < 16; m <<= 1){
      ps += __shfl_xor(ps, m, 64);
      pd += __shfl_xor(pd, m, 64);
    }
    long r = rbase + slot + i*SLOTS;
    if ((t & 15) == 0){
      asrc[r*HTOT + head] = ps; adst[r*HTOT + head] = pd;
    }
    *(float4*)&XW[r*C + c4] = acc[i];
  }
}

// ---------------- aggregation: online softmax + weighted sum + fused alpha/final ------
// 1 wave per dst node. Gather layout: H==2 (C=128): lanes 0-31 = edge j,
// lanes 32-63 = edge j+1, each lane loads float4 (1KB/wave/instr).
// H==1 (C=64): 4 edges per load instruction.
// LAYER: 1 = fin=x0(emb)+0.5*e1, write hbuf=relu
//        2 = fin+=0.5*e2,        write hbuf=relu
//        3 = out=(fin+x3)/4 to both output slots
template<int H, int LAYER>
__global__ __launch_bounds__(256) void aggregate_k(
    const float* __restrict__ XW, const float* __restrict__ asrc, const float* __restrict__ adst,
    const int* __restrict__ row_start, const int* __restrict__ colsrc, const int* __restrict__ eids,
    const float* __restrict__ bias, float* __restrict__ aout,
    float* __restrict__ hbuf, float* __restrict__ fin,
    const float* __restrict__ embi, const float* __restrict__ embu, const float* __restrict__ embf,
    float* __restrict__ outp)
{
  constexpr int C = H*64;
  int wid  = (blockIdx.x*256 + threadIdx.x) >> 6;
  int lane = threadIdx.x & 63;
  if (wid >= NN) return;
  int n0 = row_start[wid], n1 = row_start[wid+1];
  int segLen = n1 - n0;

  float ad[H];
  if constexpr (H==2){ float2 t = ((const float2*)adst)[wid]; ad[0]=t.x; ad[1]=t.y; }
  else                 ad[0] = adst[wid];

  // lane decomposition for the gather phase
  int half, lown;
  if constexpr (H==2){ half = lane>>5; lown = lane&31; }
  else               { half = lane>>4; lown = lane&15; }
  const int hd = (H==2) ? (lown>>4) : 0;

  float mx[H], den[H];
  #pragma unroll
  for (int h=0; h<H; ++h){ mx[h] = -3.402823466e38f; den[h] = 0.f; }
  float4 acc = make_float4(0,0,0,0);

  int s = 0, eid = 0;
  float p[H];
  #pragma unroll
  for (int h=0; h<H; ++h) p[h] = 0.f;

  for (int base = n0; base < n1; base += 64){
    int cnt = n1 - base; if (cnt > 64) cnt = 64;
    float e[H];
    #pragma unroll
    for (int h=0; h<H; ++h) e[h] = -3.402823466e38f;
    if (lane < cnt){
      s   = colsrc[base + lane];
      eid = eids[base + lane];
      if constexpr (H==2){
        float2 a = ((const float2*)asrc)[s];
        e[0] = leaky(a.x + ad[0]); e[1] = leaky(a.y + ad[1]);
      } else {
        e[0] = leaky(asrc[s] + ad[0]);
      }
    }
    float sc[H];
    #pragma unroll
    for (int h=0; h<H; ++h){
      float bm = e[h];
      #pragma unroll
      for (int m=1; m<64; m<<=1) bm = fmaxf(bm, __shfl_xor(bm, m, 64));
      float nm = fmaxf(mx[h], bm);
      sc[h] = __expf(mx[h] - nm);
      p[h]  = (lane < cnt) ? __expf(e[h] - nm) : 0.f;
      den[h] = den[h]*sc[h] + p[h];
      mx[h] = nm;
    }
    {
      float asc = (H==2) ? sc[hd] : sc[0];
      acc.x *= asc; acc.y *= asc; acc.z *= asc; acc.w *= asc;
    }

    if constexpr (H==2){
      for (int j = 0; j < cnt; j += 8){
        float4 v[4]; float q[4];
        #pragma unroll
        for (int u=0; u<4; ++u){
          int ei  = j + 2*u + half;
          int eic = ei < cnt ? ei : 0;
          int su  = __shfl(s, eic, 64);
          float q0 = __shfl(p[0], eic, 64);
          float q1 = __shfl(p[1], eic, 64);
          q[u] = (ei < cnt) ? (hd ? q1 : q0) : 0.f;
          v[u] = *(const float4*)&XW[(long)su*C + lown*4];
        }
        #pragma unroll
        for (int u=0; u<4; ++u){
          acc.x = fmaf(q[u], v[u].x, acc.x);
          acc.y = fmaf(q[u], v[u].y, acc.y);
          acc.z = fmaf(q[u], v[u].z, acc.z);
          acc.w = fmaf(q[u], v[u].w, acc.w);
        }
      }
    } else {
      for (int j = 0; j < cnt; j += 16){
        float4 v[4]; float q[4];
        #pragma unroll
        for (int u=0; u<4; ++u){
          int ei  = j + 4*u + half;
          int eic = ei < cnt ? ei : 0;
          int su  = __shfl(s, eic, 64);
          q[u] = (ei < cnt) ? __shfl(p[0], eic, 64) : 0.f;
          v[u] = *(const float4*)&XW[(long)su*C + lown*4];
        }
        #pragma unroll
        for (int u=0; u<4; ++u){
          acc.x = fmaf(q[u], v[u].x, acc.x);
          acc.y = fmaf(q[u], v[u].y, acc.y);
          acc.z = fmaf(q[u], v[u].z, acc.z);
          acc.w = fmaf(q[u], v[u].w, acc.w);
        }
      }
    }
  }

  float idv[H];
  #pragma unroll
  for (int h=0; h<H; ++h){
    #pragma unroll
    for (int m=1; m<64; m<<=1) den[h] += __shfl_xor(den[h], m, 64);
    idv[h] = 1.0f/(den[h] + 1e-16f);
  }

  // combine edge-parity halves
  acc.x += __shfl_xor(acc.x, 32, 64); acc.y += __shfl_xor(acc.y, 32, 64);
  acc.z += __shfl_xor(acc.z, 32, 64); acc.w += __shfl_xor(acc.w, 32, 64);
  if constexpr (H==1){
    acc.x += __shfl_xor(acc.x, 16, 64); acc.y += __shfl_xor(acc.y, 16, 64);
    acc.z += __shfl_xor(acc.z, 16, 64); acc.w += __shfl_xor(acc.w, 16, 64);
  }

  float4 b4 = *(const float4*)&bias[lown*4];
  float myId = (H==2) ? idv[hd] : idv[0];
  float4 o;
  o.x = acc.x*myId + b4.x; o.y = acc.y*myId + b4.y;
  o.z = acc.z*myId + b4.z; o.w = acc.w*myId + b4.w;

  if constexpr (LAYER==1 || LAYER==2){
    if (half == 0){
      float4 r = make_float4(fmaxf(o.x,0.f), fmaxf(o.y,0.f), fmaxf(o.z,0.f), fmaxf(o.w,0.f));
      *(float4*)&hbuf[(long)wid*C + lown*4] = r;
    }
    // head0 + head1 per feature d: lanes lown<16 pair with lown+16
    float4 f;
    f.x = o.x + __shfl_xor(o.x, 16, 64);
    f.y = o.y + __shfl_xor(o.y, 16, 64);
    f.z = o.z + __shfl_xor(o.z, 16, 64);
    f.w = o.w + __shfl_xor(o.w, 16, 64);
    if (half == 0 && lown < 16){
      float4* fp = (float4*)&fin[(long)wid*64 + lown*4];
      if constexpr (LAYER==1){
        long gi = (long)wid*16 + lown;
        float4 x0;
        if      (gi < (long)I_N*16)       x0 = ((const float4*)embi)[gi];
        else if (gi < (long)(I_N+U_N)*16) x0 = ((const float4*)embu)[gi - (long)I_N*16];
        else                              x0 = ((const float4*)embf)[gi - (long)(I_N+U_N)*16];
        *fp = make_float4(x0.x + f.x*0.5f, x0.y + f.y*0.5f, x0.z + f.z*0.5f, x0.w + f.w*0.5f);
      } else {
        float4 cur = *fp;
        *fp = make_float4(cur.x + f.x*0.5f, cur.y + f.y*0.5f, cur.z + f.z*0.5f, cur.w + f.w*0.5f);
      }
    }
  } else {
    // LAYER 3: final = (fin + x3)/4 -> both output copies
    if (lane < 16){
      float4 cur = *(const float4*)&fin[(long)wid*64 + lown*4];
      float4 tot = make_float4((cur.x + o.x)*0.25f, (cur.y + o.y)*0.25f,
                               (cur.z + o.z)*0.25f, (cur.w + o.w)*0.25f);
      ((float4*)outp)[(long)wid*16 + lown]            = tot;
      ((float4*)outp)[(long)(NN + wid)*16 + lown]     = tot;
    }
  }

  // fused alpha output
  if (segLen <= 64){
    if (lane < segLen){
      if constexpr (H==2)
        ((float2*)aout)[eid] = make_float2(p[0]*idv[0], p[1]*idv[1]);
      else
        aout[eid] = p[0]*idv[0];
    }
  } else {
    for (int base = n0; base < n1; base += 64){
      int cnt = n1 - base; if (cnt > 64) cnt = 64;
      if (lane < cnt){
        int ss = colsrc[base + lane];
        int ee = eids[base + lane];
        if constexpr (H==2){
          float2 a = ((const float2*)asrc)[ss];
          float w0 = __expf(leaky(a.x + ad[0]) - mx[0]) * idv[0];
          float w1 = __expf(leaky(a.y + ad[1]) - mx[1]) * idv[1];
          ((float2*)aout)[ee] = make_float2(w0, w1);
        } else {
          aout[ee] = __expf(leaky(asrc[ss] + ad[0]) - mx[0]) * idv[0];
        }
      }
    }
  }
}

extern "C" void kernel_launch(void* const* d_in, const int* in_sizes, int n_in,
                              void* d_out, int out_size, void* d_ws, size_t ws_size,
                              hipStream_t stream)
{
  (void)in_sizes; (void)n_in; (void)out_size; (void)ws_size;
  const int*   eidx  = (const int*)d_in[0];
  const int*   esrc  = eidx;
  const int*   edst  = eidx + EE;
  const float* emb_i = (const float*)d_in[1];
  const float* emb_u = (const float*)d_in[2];
  const float* emb_f = (const float*)d_in[3];
  const float* W1    = (const float*)d_in[4];
  const float* as1   = (const float*)d_in[5];
  const float* ad1   = (const float*)d_in[6];
  const float* b1    = (const float*)d_in[7];
  const float* W2    = (const float*)d_in[8];
  const float* as2   = (const float*)d_in[9];
  const float* ad2   = (const float*)d_in[10];
  const float* b2    = (const float*)d_in[11];
  const float* W3    = (const float*)d_in[12];
  const float* as3   = (const float*)d_in[13];
  const float* ad3   = (const float*)d_in[14];
  const float* b3    = (const float*)d_in[15];
  float* out = (float*)d_out;

  // workspace layout (256B aligned)
  char* p = (char*)d_ws;
  auto alloc = [&](size_t bytes)->char* {
    char* r = p; p += (bytes + 255) & ~(size_t)255; return r;
  };
  float* fin    = (float*)alloc((size_t)NN*64*4);
  float* hbuf   = (float*)alloc((size_t)NN*128*4);
  float* xw     = (float*)alloc((size_t)NN*128*4);
  float* asrc   = (float*)alloc((size_t)NN*2*4);
  float* adst   = (float*)alloc((size_t)NN*2*4);
  int* counts    = (int*)alloc((size_t)NN*4);
  int* row_start = (int*)alloc((size_t)(NN+1)*4);
  int* cursor    = (int*)alloc((size_t)NN*4);
  int* colsrc    = (int*)alloc((size_t)ETOT*4);
  int* eids      = (int*)alloc((size_t)ETOT*4);
  int* partials  = (int*)alloc(512*4);

  constexpr int NB_N  = (NN  +255)/256;   // 391
  constexpr int NB_E  = (EE  +255)/256;   // 4688
  constexpr int NB_ET = (ETOT+255)/256;   // 5079

  float* alpha1 = out + (size_t)12800000;
  float* alpha2 = out + (size_t)15400000;
  float* alpha3 = out + (size_t)18000000;

  // CSR build (shared by all layers)
  init_counts_k<<<NB_N ,256,0,stream>>>(counts);
  count_k      <<<NB_E ,256,0,stream>>>(edst, counts);
  scan_blk_k   <<<NB_N ,256,0,stream>>>(counts, row_start, partials);
  scan_part_k  <<<1    ,512,0,stream>>>(partials, NB_N);
  scan_fix_k   <<<NB_N ,256,0,stream>>>(row_start, partials, cursor);
  scatter_k    <<<NB_ET,256,0,stream>>>(esrc, edst, cursor, colsrc, eids);

  // ---- Layer 1: K=64 -> C=128 (H=2), X = concat(embeddings) ----
  gemm_att_k<64,128,64,32,true><<<NN/32,256,0,stream>>>(emb_i, emb_u, emb_f, W1, as1, ad1, xw, asrc, adst);
  aggregate_k<2,1><<<NN/4,256,0,stream>>>(xw, asrc, adst, row_start, colsrc, eids, b1, alpha1,
                                          hbuf, fin, emb_i, emb_u, emb_f, nullptr);

  // ---- Layer 2: K=128 -> C=128 (H=2) ----
  gemm_att_k<128,128,64,32,false><<<NN/32,256,0,stream>>>(hbuf, nullptr, nullptr, W2, as2, ad2, xw, asrc, adst);
  aggregate_k<2,2><<<NN/4,256,0,stream>>>(xw, asrc, adst, row_start, colsrc, eids, b2, alpha2,
                                          hbuf, fin, nullptr, nullptr, nullptr, nullptr);

  // ---- Layer 3: K=128 -> C=64 (H=1), fused final write ----
  gemm_att_k<128,64,128,32,false><<<NN/32,256,0,stream>>>(hbuf, nullptr, nullptr, W3, as3, ad3, xw, asrc, adst);
  aggregate_k<1,3><<<NN/4,256,0,stream>>>(xw, asrc, adst, row_start, colsrc, eids, b3, alpha3,
                                          nullptr, fin, nullptr, nullptr, nullptr, out);
}

// Round 4
// 596.438 us; speedup vs baseline: 1.4407x; 1.1638x over previous
//
#include <hip/hip_runtime.h>
#include <hip/hip_fp16.h>
#include <math.h>

// Problem constants (fixed by reference)
constexpr int I_N = 40000, U_N = 30000, F_N = 30000;
constexpr int NN   = 100000;           // total nodes
constexpr int EE   = 1200000;          // edges (without self loops)
constexpr int ETOT = EE + NN;          // edges + self loops

__device__ __forceinline__ float leaky(float x){ return x > 0.f ? x : 0.2f*x; }

// ---------------- CSR build ----------------
__global__ __launch_bounds__(256) void init_counts_k(int* counts){
  int i = blockIdx.x*256 + threadIdx.x;
  if (i < NN) counts[i] = 1;                   // self loop
}

__global__ __launch_bounds__(256) void count_k(const int* __restrict__ edst, int* counts){
  int e = blockIdx.x*256 + threadIdx.x;
  if (e < EE) atomicAdd(&counts[edst[e]], 1);
}

__global__ __launch_bounds__(256) void scan_blk_k(const int* __restrict__ counts,
                                                  int* __restrict__ row_start,
                                                  int* __restrict__ partials){
  __shared__ int sm[256];
  int t = threadIdx.x, i = blockIdx.x*256 + t;
  int v = (i < NN) ? counts[i] : 0;
  sm[t] = v; __syncthreads();
  for (int off=1; off<256; off<<=1){
    int x = (t >= off) ? sm[t-off] : 0;
    __syncthreads();
    sm[t] += x;
    __syncthreads();
  }
  if (i < NN) row_start[i] = sm[t] - v;        // exclusive
  if (t == 255) partials[blockIdx.x] = sm[255];
}

__global__ __launch_bounds__(512) void scan_part_k(int* partials, int nb){
  __shared__ int sm[512];
  int t = threadIdx.x;
  int v = (t < nb) ? partials[t] : 0;
  sm[t] = v; __syncthreads();
  for (int off=1; off<512; off<<=1){
    int x = (t >= off) ? sm[t-off] : 0;
    __syncthreads();
    sm[t] += x;
    __syncthreads();
  }
  if (t < nb) partials[t] = sm[t] - v;         // exclusive
}

__global__ __launch_bounds__(256) void scan_fix_k(int* row_start, const int* __restrict__ partials,
                                                  int* cursor){
  int i = blockIdx.x*256 + threadIdx.x;
  if (i < NN){
    int v = row_start[i] + partials[blockIdx.x];
    row_start[i] = v;
    cursor[i]    = v;
  }
  if (i == 0) row_start[NN] = ETOT;
}

__global__ __launch_bounds__(256) void scatter_k(const int* __restrict__ esrc,
                                                 const int* __restrict__ edst,
                                                 int* cursor, int* __restrict__ colsrc,
                                                 int* __restrict__ eids){
  int e = blockIdx.x*256 + threadIdx.x;
  if (e < EE){
    int d = edst[e];
    int p = atomicAdd(&cursor[d], 1);
    colsrc[p] = esrc[e];
    eids[p]   = e;
  } else if (e < ETOT){
    int i = e - EE;                            // self loop
    int p = atomicAdd(&cursor[i], 1);
    colsrc[p] = i;
    eids[p]   = e;
  }
}

// ---------------- GEMM (+ fused attention dot products) ----------------
// XW(fp16) = X @ W (W row-major K x C), plus fp32 asrc/adst epilogue. K-tiled.
// CONCAT: X is the virtual concat [Xa;Xb;Xc] (embeddings), row-width K.
template<int K, int C, int KTILE, int RPB, bool CONCAT>
__global__ __launch_bounds__(256) void gemm_att_k(
    const float* __restrict__ Xa, const float* __restrict__ Xb, const float* __restrict__ Xc,
    const float* __restrict__ W,
    const float* __restrict__ atts, const float* __restrict__ attd,
    __half* __restrict__ XWH, float* __restrict__ asrc, float* __restrict__ adst)
{
  constexpr int TPR   = C/4;        // threads per row
  constexpr int SLOTS = 256/TPR;    // concurrent rows
  constexpr int RPT   = RPB/SLOTS;  // rows per thread
  constexpr int HTOT  = C/64;
  __shared__ float Ws[KTILE*C];
  __shared__ float Xs[RPB*K];
  int t = threadIdx.x;
  long rbase = (long)blockIdx.x * RPB;

  if constexpr (CONCAT){
    for (int i = t; i < RPB*K/4; i += 256){
      long gi = rbase*(K/4) + i;               // float4 index in concat space
      float4 v;
      if      (gi < (long)I_N*(K/4))          v = ((const float4*)Xa)[gi];
      else if (gi < (long)(I_N+U_N)*(K/4))    v = ((const float4*)Xb)[gi - (long)I_N*(K/4)];
      else                                    v = ((const float4*)Xc)[gi - (long)(I_N+U_N)*(K/4)];
      ((float4*)Xs)[i] = v;
    }
  } else {
    for (int i = t; i < RPB*K/4; i += 256)
      ((float4*)Xs)[i] = ((const float4*)(Xa + rbase*K))[i];
  }

  int slot = t / TPR;
  int c4   = (t % TPR)*4;
  float4 acc[RPT];
  #pragma unroll
  for (int i = 0; i < RPT; ++i) acc[i] = make_float4(0,0,0,0);

  for (int kt = 0; kt < K; kt += KTILE){
    __syncthreads();
    for (int i = t; i < KTILE*C/4; i += 256)
      ((float4*)Ws)[i] = ((const float4*)(W + (long)kt*C))[i];
    __syncthreads();
    #pragma unroll 2
    for (int k = 0; k < KTILE; k += 4){
      float4 xv[RPT];
      #pragma unroll
      for (int i = 0; i < RPT; ++i)
        xv[i] = *(const float4*)&Xs[(slot + i*SLOTS)*K + kt + k];
      #pragma unroll
      for (int kk = 0; kk < 4; ++kk){
        float4 w = *(const float4*)&Ws[(k+kk)*C + c4];
        #pragma unroll
        for (int i = 0; i < RPT; ++i){
          float xvv = (kk==0)?xv[i].x:(kk==1)?xv[i].y:(kk==2)?xv[i].z:xv[i].w;
          acc[i].x = fmaf(xvv,w.x,acc[i].x); acc[i].y = fmaf(xvv,w.y,acc[i].y);
          acc[i].z = fmaf(xvv,w.z,acc[i].z); acc[i].w = fmaf(xvv,w.w,acc[i].w);
        }
      }
    }
  }

  int head = c4 >> 6;
  float4 as4 = *(const float4*)&atts[head*64 + (c4&63)];
  float4 ad4 = *(const float4*)&attd[head*64 + (c4&63)];
  #pragma unroll
  for (int i = 0; i < RPT; ++i){
    float ps = acc[i].x*as4.x + acc[i].y*as4.y + acc[i].z*as4.z + acc[i].w*as4.w;
    float pd = acc[i].x*ad4.x + acc[i].y*ad4.y + acc[i].z*ad4.z + acc[i].w*ad4.w;
    #pragma unroll
    for (int m = 1; m < 16; m <<= 1){
      ps += __shfl_xor(ps, m, 64);
      pd += __shfl_xor(pd, m, 64);
    }
    long r = rbase + slot + i*SLOTS;
    if ((t & 15) == 0){
      asrc[r*HTOT + head] = ps; adst[r*HTOT + head] = pd;
    }
    union { __half2 h2[2]; uint2 u2; } pk;
    pk.h2[0] = __floats2half2_rn(acc[i].x, acc[i].y);
    pk.h2[1] = __floats2half2_rn(acc[i].z, acc[i].w);
    *(uint2*)&XWH[r*C + c4] = pk.u2;
  }
}

// ---------------- aggregation: online softmax + weighted sum + fused alpha/final ------
// 1 wave per dst node, XW rows in fp16.
// H==2 (row 256B): 4 edges per wave-load; lane = slot(lane>>4) x colgroup(lane&15, 8 cols).
// H==1 (row 128B): 8 edges per wave-load; slot = lane>>3, colgroup = lane&7.
// LAYER: 1 = fin=x0(emb)+0.5*e1, hbuf=relu ; 2 = fin+=0.5*e2, hbuf=relu
//        3 = out=(fin+x3)/4 to both output slots
template<int H, int LAYER>
__global__ __launch_bounds__(256) void aggregate_k(
    const __half* __restrict__ XWH, const float* __restrict__ asrc, const float* __restrict__ adst,
    const int* __restrict__ row_start, const int* __restrict__ colsrc, const int* __restrict__ eids,
    const float* __restrict__ bias, float* __restrict__ aout,
    float* __restrict__ hbuf, float* __restrict__ fin,
    const float* __restrict__ embi, const float* __restrict__ embu, const float* __restrict__ embf,
    float* __restrict__ outp)
{
  constexpr int C = H*64;
  int wid  = (blockIdx.x*256 + threadIdx.x) >> 6;
  int lane = threadIdx.x & 63;
  if (wid >= NN) return;
  int n0 = row_start[wid], n1 = row_start[wid+1];
  int segLen = n1 - n0;

  float ad[H];
  if constexpr (H==2){ float2 t = ((const float2*)adst)[wid]; ad[0]=t.x; ad[1]=t.y; }
  else                 ad[0] = adst[wid];

  constexpr int SL_SH = (H==2) ? 4 : 3;       // slot shift
  const int slot = lane >> SL_SH;
  const int cg   = lane & ((1<<SL_SH)-1);     // col-group: 8 cols each
  const int hd   = (H==2) ? (cg>>3) : 0;      // head of this lane's cols

  float mx[H], den[H];
  #pragma unroll
  for (int h=0; h<H; ++h){ mx[h] = -3.402823466e38f; den[h] = 0.f; }
  float accv[8];
  #pragma unroll
  for (int i=0;i<8;++i) accv[i] = 0.f;

  int s = 0, eid = 0;
  float p[H];
  #pragma unroll
  for (int h=0; h<H; ++h) p[h] = 0.f;

  for (int base = n0; base < n1; base += 64){
    int cnt = n1 - base; if (cnt > 64) cnt = 64;
    float e[H];
    #pragma unroll
    for (int h=0; h<H; ++h) e[h] = -3.402823466e38f;
    if (lane < cnt){
      s   = colsrc[base + lane];
      eid = eids[base + lane];
      if constexpr (H==2){
        float2 a = ((const float2*)asrc)[s];
        e[0] = leaky(a.x + ad[0]); e[1] = leaky(a.y + ad[1]);
      } else {
        e[0] = leaky(asrc[s] + ad[0]);
      }
    }
    float sc[H];
    #pragma unroll
    for (int h=0; h<H; ++h){
      float bm = e[h];
      #pragma unroll
      for (int m=1; m<64; m<<=1) bm = fmaxf(bm, __shfl_xor(bm, m, 64));
      float nm = fmaxf(mx[h], bm);
      p[h] = (lane < cnt) ? __expf(e[h] - nm) : 0.f;
      if (base == n0){
        den[h] = p[h]; sc[h] = 1.f;
      } else {
        sc[h] = __expf(mx[h] - nm);
        den[h] = den[h]*sc[h] + p[h];
      }
      mx[h] = nm;
    }
    if (base != n0){
      float asc = (H==2) ? sc[hd] : sc[0];
      #pragma unroll
      for (int i=0;i<8;++i) accv[i] *= asc;
    }

    constexpr int EPI = 64 >> SL_SH;           // edges per inner iter (per load pair: 2*EPI/2)
    for (int j = 0; j < cnt; j += 2*EPI){
      float4 raw[2]; float q[2];
      #pragma unroll
      for (int u=0; u<2; ++u){
        int ei  = j + u*EPI + slot;
        int eic = ei < cnt ? ei : 0;
        int su  = __shfl(s, eic, 64);
        if constexpr (H==2){
          float q0 = __shfl(p[0], eic, 64);
          float q1 = __shfl(p[1], eic, 64);
          q[u] = (ei < cnt) ? (hd ? q1 : q0) : 0.f;
        } else {
          float q0 = __shfl(p[0], eic, 64);
          q[u] = (ei < cnt) ? q0 : 0.f;
        }
        raw[u] = *(const float4*)&XWH[(long)su*C + cg*8];
      }
      #pragma unroll
      for (int u=0; u<2; ++u){
        union { float4 f4; __half2 h2[4]; } cv; cv.f4 = raw[u];
        #pragma unroll
        for (int i=0;i<4;++i){
          float2 f = __half22float2(cv.h2[i]);
          accv[2*i]   = fmaf(q[u], f.x, accv[2*i]);
          accv[2*i+1] = fmaf(q[u], f.y, accv[2*i+1]);
        }
      }
    }
  }

  float idv[H];
  #pragma unroll
  for (int h=0; h<H; ++h){
    #pragma unroll
    for (int m=1; m<64; m<<=1) den[h] += __shfl_xor(den[h], m, 64);
    idv[h] = 1.0f/(den[h] + 1e-16f);
  }

  // combine edge-slot partial sums: lanes with same cg
  #pragma unroll
  for (int i=0;i<8;++i){
    if constexpr (H==1) accv[i] += __shfl_xor(accv[i], 8, 64);
    accv[i] += __shfl_xor(accv[i], 16, 64);
    accv[i] += __shfl_xor(accv[i], 32, 64);
  }

  float myId = (H==2) ? idv[hd] : idv[0];
  float4 b0 = *(const float4*)&bias[cg*8];
  float4 b1 = *(const float4*)&bias[cg*8 + 4];
  float o[8];
  o[0]=accv[0]*myId+b0.x; o[1]=accv[1]*myId+b0.y; o[2]=accv[2]*myId+b0.z; o[3]=accv[3]*myId+b0.w;
  o[4]=accv[4]*myId+b1.x; o[5]=accv[5]*myId+b1.y; o[6]=accv[6]*myId+b1.z; o[7]=accv[7]*myId+b1.w;

  if constexpr (LAYER==1 || LAYER==2){
    if (lane < 16){
      float4 r0 = make_float4(fmaxf(o[0],0.f), fmaxf(o[1],0.f), fmaxf(o[2],0.f), fmaxf(o[3],0.f));
      float4 r1 = make_float4(fmaxf(o[4],0.f), fmaxf(o[5],0.f), fmaxf(o[6],0.f), fmaxf(o[7],0.f));
      *(float4*)&hbuf[(long)wid*C + cg*8]     = r0;
      *(float4*)&hbuf[(long)wid*C + cg*8 + 4] = r1;
    }
    // head0 + head1 per feature d: lane l (cg<8) pairs with l+8
    float f[8];
    #pragma unroll
    for (int i=0;i<8;++i) f[i] = o[i] + __shfl_xor(o[i], 8, 64);
    if (lane < 8){
      float4 f0 = make_float4(f[0],f[1],f[2],f[3]);
      float4 f1 = make_float4(f[4],f[5],f[6],f[7]);
      float4* fp = (float4*)&fin[(long)wid*64 + lane*8];
      if constexpr (LAYER==1){
        const float4* src; long off;
        if      (wid < I_N)      { src=(const float4*)embi; off=(long)wid*16; }
        else if (wid < I_N+U_N)  { src=(const float4*)embu; off=(long)(wid-I_N)*16; }
        else                     { src=(const float4*)embf; off=(long)(wid-I_N-U_N)*16; }
        float4 xa = src[off + lane*2], xb = src[off + lane*2 + 1];
        fp[0] = make_float4(xa.x+f0.x*0.5f, xa.y+f0.y*0.5f, xa.z+f0.z*0.5f, xa.w+f0.w*0.5f);
        fp[1] = make_float4(xb.x+f1.x*0.5f, xb.y+f1.y*0.5f, xb.z+f1.z*0.5f, xb.w+f1.w*0.5f);
      } else {
        float4 ca = fp[0], cb = fp[1];
        fp[0] = make_float4(ca.x+f0.x*0.5f, ca.y+f0.y*0.5f, ca.z+f0.z*0.5f, ca.w+f0.w*0.5f);
        fp[1] = make_float4(cb.x+f1.x*0.5f, cb.y+f1.y*0.5f, cb.z+f1.z*0.5f, cb.w+f1.w*0.5f);
      }
    }
  } else {
    // LAYER 3: final = (fin + x3)/4 -> both output copies
    if (lane < 8){
      const float4* fp = (const float4*)&fin[(long)wid*64 + lane*8];
      float4 ca = fp[0], cb = fp[1];
      float4 t0 = make_float4((ca.x+o[0])*0.25f,(ca.y+o[1])*0.25f,(ca.z+o[2])*0.25f,(ca.w+o[3])*0.25f);
      float4 t1 = make_float4((cb.x+o[4])*0.25f,(cb.y+o[5])*0.25f,(cb.z+o[6])*0.25f,(cb.w+o[7])*0.25f);
      ((float4*)outp)[(long)wid*16 + lane*2]            = t0;
      ((float4*)outp)[(long)wid*16 + lane*2 + 1]        = t1;
      ((float4*)outp)[(long)(NN+wid)*16 + lane*2]       = t0;
      ((float4*)outp)[(long)(NN+wid)*16 + lane*2 + 1]   = t1;
    }
  }

  // fused alpha output
  if (segLen <= 64){
    if (lane < segLen){
      if constexpr (H==2)
        ((float2*)aout)[eid] = make_float2(p[0]*idv[0], p[1]*idv[1]);
      else
        aout[eid] = p[0]*idv[0];
    }
  } else {
    for (int base = n0; base < n1; base += 64){
      int cnt = n1 - base; if (cnt > 64) cnt = 64;
      if (lane < cnt){
        int ss = colsrc[base + lane];
        int ee = eids[base + lane];
        if constexpr (H==2){
          float2 a = ((const float2*)asrc)[ss];
          float w0 = __expf(leaky(a.x + ad[0]) - mx[0]) * idv[0];
          float w1 = __expf(leaky(a.y + ad[1]) - mx[1]) * idv[1];
          ((float2*)aout)[ee] = make_float2(w0, w1);
        } else {
          aout[ee] = __expf(leaky(asrc[ss] + ad[0]) - mx[0]) * idv[0];
        }
      }
    }
  }
}

extern "C" void kernel_launch(void* const* d_in, const int* in_sizes, int n_in,
                              void* d_out, int out_size, void* d_ws, size_t ws_size,
                              hipStream_t stream)
{
  (void)in_sizes; (void)n_in; (void)out_size; (void)ws_size;
  const int*   eidx  = (const int*)d_in[0];
  const int*   esrc  = eidx;
  const int*   edst  = eidx + EE;
  const float* emb_i = (const float*)d_in[1];
  const float* emb_u = (const float*)d_in[2];
  const float* emb_f = (const float*)d_in[3];
  const float* W1    = (const float*)d_in[4];
  const float* as1   = (const float*)d_in[5];
  const float* ad1   = (const float*)d_in[6];
  const float* b1    = (const float*)d_in[7];
  const float* W2    = (const float*)d_in[8];
  const float* as2   = (const float*)d_in[9];
  const float* ad2   = (const float*)d_in[10];
  const float* b2    = (const float*)d_in[11];
  const float* W3    = (const float*)d_in[12];
  const float* as3   = (const float*)d_in[13];
  const float* ad3   = (const float*)d_in[14];
  const float* b3    = (const float*)d_in[15];
  float* out = (float*)d_out;

  // workspace layout (256B aligned)
  char* p = (char*)d_ws;
  auto alloc = [&](size_t bytes)->char* {
    char* r = p; p += (bytes + 255) & ~(size_t)255; return r;
  };
  float*  fin  = (float*)alloc((size_t)NN*64*4);
  float*  hbuf = (float*)alloc((size_t)NN*128*4);
  __half* xwh  = (__half*)alloc((size_t)NN*128*2);
  float*  asrc = (float*)alloc((size_t)NN*2*4);
  float*  adst = (float*)alloc((size_t)NN*2*4);
  int* counts    = (int*)alloc((size_t)NN*4);
  int* row_start = (int*)alloc((size_t)(NN+1)*4);
  int* cursor    = (int*)alloc((size_t)NN*4);
  int* colsrc    = (int*)alloc((size_t)ETOT*4);
  int* eids      = (int*)alloc((size_t)ETOT*4);
  int* partials  = (int*)alloc(512*4);

  constexpr int NB_N  = (NN  +255)/256;   // 391
  constexpr int NB_E  = (EE  +255)/256;   // 4688
  constexpr int NB_ET = (ETOT+255)/256;   // 5079

  float* alpha1 = out + (size_t)12800000;
  float* alpha2 = out + (size_t)15400000;
  float* alpha3 = out + (size_t)18000000;

  // CSR build (shared by all layers)
  init_counts_k<<<NB_N ,256,0,stream>>>(counts);
  count_k      <<<NB_E ,256,0,stream>>>(edst, counts);
  scan_blk_k   <<<NB_N ,256,0,stream>>>(counts, row_start, partials);
  scan_part_k  <<<1    ,512,0,stream>>>(partials, NB_N);
  scan_fix_k   <<<NB_N ,256,0,stream>>>(row_start, partials, cursor);
  scatter_k    <<<NB_ET,256,0,stream>>>(esrc, edst, cursor, colsrc, eids);

  // ---- Layer 1: K=64 -> C=128 (H=2), X = concat(embeddings) ----
  gemm_att_k<64,128,64,32,true><<<NN/32,256,0,stream>>>(emb_i, emb_u, emb_f, W1, as1, ad1, xwh, asrc, adst);
  aggregate_k<2,1><<<NN/4,256,0,stream>>>(xwh, asrc, adst, row_start, colsrc, eids, b1, alpha1,
                                          hbuf, fin, emb_i, emb_u, emb_f, nullptr);

  // ---- Layer 2: K=128 -> C=128 (H=2) ----
  gemm_att_k<128,128,64,32,false><<<NN/32,256,0,stream>>>(hbuf, nullptr, nullptr, W2, as2, ad2, xwh, asrc, adst);
  aggregate_k<2,2><<<NN/4,256,0,stream>>>(xwh, asrc, adst, row_start, colsrc, eids, b2, alpha2,
                                          hbuf, fin, nullptr, nullptr, nullptr, nullptr);

  // ---- Layer 3: K=128 -> C=64 (H=1), fused final write ----
  gemm_att_k<128,64,128,32,false><<<NN/32,256,0,stream>>>(hbuf, nullptr, nullptr, W3, as3, ad3, xwh, asrc, adst);
  aggregate_k<1,3><<<NN/4,256,0,stream>>>(xwh, asrc, adst, row_start, colsrc, eids, b3, alpha3,
                                          nullptr, fin, nullptr, nullptr, nullptr, out);
}